// Round 3
// baseline (1110.200 us; speedup 1.0000x reference)
//
#include <hip/hip_runtime.h>
#include <math.h>

#define TPB 256
#define GTPB 128
#define ATPB 1024
#define NBLK 256        // blocks for hist/scatter passes
#define BUCKET 256      // dst nodes per bucket
#define SRCMASK 0x1FFFF // 17 bits for src (n < 131072)

namespace {

constexpr int IN_FEAT = 512;
constexpr int HID = 16;

__device__ __forceinline__ void load_edge(const int* __restrict__ ei32,
                                          const long long* __restrict__ ei64,
                                          int flag, int e, int E, int& s, int& d) {
  if (flag) {
    s = (int)ei64[e];
    d = (int)ei64[(long long)E + e];
  } else {
    s = ei32[e];
    d = ei32[(long long)E + e];
  }
}

// ---- edge dtype detect: int64 (all high words zero) vs int32 ----
__global__ void k_detect(const int* __restrict__ ei32, int* __restrict__ flag) {
  __shared__ int red[TPB];
  int t = threadIdx.x;
  int v = 0;
  for (int i = t; i < 2048; i += TPB) v |= ei32[2 * i + 1];
  red[t] = v;
  __syncthreads();
  for (int s = TPB / 2; s > 0; s >>= 1) {
    if (t < s) red[t] |= red[t + s];
    __syncthreads();
  }
  if (t == 0) *flag = (red[0] == 0) ? 1 : 0;  // 1 => int64 layout
}

// ---- per-(bucket,block) histogram of dst>>8 ----
__global__ void k_hist(const int* __restrict__ ei32, const long long* __restrict__ ei64,
                       const int* __restrict__ flag, int* __restrict__ mat,
                       int E, int chunk, int NB) {
  __shared__ int h[512];
  int t = threadIdx.x, b = blockIdx.x;
  for (int k = t; k < 512; k += TPB) h[k] = 0;
  __syncthreads();
  int fl = *flag;
  int e0 = b * chunk, e1 = min(E, e0 + chunk);
  for (int e = e0 + t; e < e1; e += TPB) {
    int d = fl ? (int)ei64[(long long)E + e] : ei32[(long long)E + e];
    atomicAdd(&h[d >> 8], 1);
  }
  __syncthreads();
  for (int k = t; k < NB; k += TPB) mat[k * NBLK + b] = h[k];
}

// ---- exclusive scan of mat[0..M) (bucket-major), single block ----
__global__ void k_scan(int* __restrict__ mat, int M) {
  __shared__ int sc[ATPB];
  int t = threadIdx.x;
  int c = (M + ATPB - 1) / ATPB;
  int i0 = t * c, i1 = min(M, i0 + c);
  int s = 0;
  for (int i = i0; i < i1; i++) s += mat[i];
  sc[t] = s;
  __syncthreads();
  for (int st = 1; st < ATPB; st <<= 1) {
    int add = (t >= st) ? sc[t - st] : 0;
    __syncthreads();
    sc[t] += add;
    __syncthreads();
  }
  int run = sc[t] - s;  // exclusive prefix
  for (int i = i0; i < i1; i++) {
    int v = mat[i];
    mat[i] = run;
    run += v;
  }
}

// ---- coarse scatter: packed = (dst&255)<<17 | src, bucket-grouped ----
__global__ void k_scatterE(const int* __restrict__ ei32, const long long* __restrict__ ei64,
                           const int* __restrict__ flag, const int* __restrict__ mat,
                           int* __restrict__ ebuf, int E, int chunk, int NB) {
  __shared__ int cur[512];
  int t = threadIdx.x, b = blockIdx.x;
  for (int k = t; k < NB; k += TPB) cur[k] = mat[k * NBLK + b];
  __syncthreads();
  int fl = *flag;
  int e0 = b * chunk, e1 = min(E, e0 + chunk);
  for (int e = e0 + t; e < e1; e += TPB) {
    int s, d;
    load_edge(ei32, ei64, fl, e, E, s, d);
    int pos = atomicAdd(&cur[d >> 8], 1);
    ebuf[pos] = ((d & 255) << 17) | s;
  }
}

// ---- per-bucket degree -> dinv (self-loop +1) ----
__global__ void k_dinv2(const int* __restrict__ mat, const int* __restrict__ ebuf,
                        float* __restrict__ dinv, int n, int E, int NB) {
  __shared__ int cnt[BUCKET];
  int t = threadIdx.x, b = blockIdx.x;
  if (t < BUCKET) cnt[t] = 1;
  __syncthreads();
  int e0 = mat[b * NBLK], e1 = (b + 1 < NB) ? mat[(b + 1) * NBLK] : E;
  for (int e = e0 + t; e < e1; e += TPB) atomicAdd(&cnt[ebuf[e] >> 17], 1);
  __syncthreads();
  int node = (b << 8) + t;
  if (t < BUCKET && node < n) dinv[node] = rsqrtf((float)cnt[t]);
}

// ---- layer1 GEMM: hs1 = (x @ W1) * dinv[row] ----
__global__ __launch_bounds__(GTPB) void k_gemm1(const float* __restrict__ x,
                                                const float* __restrict__ W1,
                                                const float* __restrict__ dinv,
                                                float* __restrict__ hs1, int n) {
  __shared__ float xs[128 * 68];
  __shared__ float wt[16 * 68];
  int t = threadIdx.x;
  int rq = t & 31, cq = t >> 5;
  float acc[4][4] = {};
  int r0 = blockIdx.x * 128;
  const float4* x4 = (const float4*)x;
  for (int ch = 0; ch < 8; ch++) {
    for (int i = t; i < 2048; i += GTPB) {
      int row = i >> 4, cc = i & 15;
      int gr = r0 + row;
      if (gr >= n) gr = n - 1;
      float4 v = x4[(long long)gr * 128 + ch * 16 + cc];
      *(float4*)&xs[row * 68 + cc * 4] = v;
    }
    for (int i = t; i < 1024; i += GTPB) {
      int kl = i >> 4, c = i & 15;
      wt[c * 68 + kl] = W1[(ch * 64 + kl) * 16 + c];
    }
    __syncthreads();
#pragma unroll 4
    for (int kk = 0; kk < 16; kk++) {
      float4 xv[4], wv[4];
#pragma unroll
      for (int ri = 0; ri < 4; ri++) xv[ri] = *(const float4*)&xs[(rq + 32 * ri) * 68 + kk * 4];
#pragma unroll
      for (int ci = 0; ci < 4; ci++) wv[ci] = *(const float4*)&wt[(4 * cq + ci) * 68 + kk * 4];
#pragma unroll
      for (int ri = 0; ri < 4; ri++)
#pragma unroll
        for (int ci = 0; ci < 4; ci++) {
          acc[ri][ci] = fmaf(xv[ri].x, wv[ci].x, acc[ri][ci]);
          acc[ri][ci] = fmaf(xv[ri].y, wv[ci].y, acc[ri][ci]);
          acc[ri][ci] = fmaf(xv[ri].z, wv[ci].z, acc[ri][ci]);
          acc[ri][ci] = fmaf(xv[ri].w, wv[ci].w, acc[ri][ci]);
        }
    }
    __syncthreads();
  }
#pragma unroll
  for (int ri = 0; ri < 4; ri++) {
    int row = r0 + rq + 32 * ri;
    if (row < n) {
      float di = dinv[row];
      float4 v = make_float4(acc[ri][0] * di, acc[ri][1] * di, acc[ri][2] * di, acc[ri][3] * di);
      *(float4*)&hs1[(long long)row * HID + 4 * cq] = v;
    }
  }
}

// ---- layer1 aggregation in LDS + bias + relu ----
__global__ __launch_bounds__(ATPB) void k_agg1(const int* __restrict__ mat,
                                               const int* __restrict__ ebuf,
                                               const float* __restrict__ hs1,
                                               const float* __restrict__ dinv,
                                               const float* __restrict__ b1,
                                               float* __restrict__ h1, int n, int E, int NB) {
  __shared__ float acc[BUCKET * 16];
  int t = threadIdx.x, b = blockIdx.x;
  int base = b << 8;
  for (int i = t; i < BUCKET * 16; i += ATPB) {
    int node = base + (i >> 4);
    acc[i] = (node < n) ? hs1[node * 16 + (i & 15)] : 0.f;  // self-loop init
  }
  __syncthreads();
  int e0 = mat[b * NBLK];
  int e1 = (b + 1 < NB) ? mat[(b + 1) * NBLK] : E;
  int sub = t & 15, slot = t >> 4;  // 64 edge slots
  int e = e0 + slot;
  for (; e + 192 < e1; e += 256) {
    int p0 = ebuf[e], p1 = ebuf[e + 64], p2 = ebuf[e + 128], p3 = ebuf[e + 192];
    float v0 = hs1[(p0 & SRCMASK) * 16 + sub];
    float v1 = hs1[(p1 & SRCMASK) * 16 + sub];
    float v2 = hs1[(p2 & SRCMASK) * 16 + sub];
    float v3 = hs1[(p3 & SRCMASK) * 16 + sub];
    atomicAdd(&acc[(p0 >> 17) * 16 + sub], v0);
    atomicAdd(&acc[(p1 >> 17) * 16 + sub], v1);
    atomicAdd(&acc[(p2 >> 17) * 16 + sub], v2);
    atomicAdd(&acc[(p3 >> 17) * 16 + sub], v3);
  }
  for (; e < e1; e += 64) {
    int p = ebuf[e];
    atomicAdd(&acc[(p >> 17) * 16 + sub], hs1[(p & SRCMASK) * 16 + sub]);
  }
  __syncthreads();
  for (int i = t; i < BUCKET * 16; i += ATPB) {
    int node = base + (i >> 4);
    if (node < n) {
      int f = i & 15;
      h1[node * 16 + f] = fmaxf(fmaf(dinv[node], acc[i], b1[f]), 0.f);
    }
  }
}

// ---- layer2 transform: hs2 = (h1 @ W2) * dinv, padded to width 8 ----
__global__ void k_layer2(const float* __restrict__ h1, const float* __restrict__ dinv,
                         const float* __restrict__ W2, float* __restrict__ hs2, int n) {
  int i = blockIdx.x * TPB + threadIdx.x;
  if (i >= n) return;
  float di = dinv[i];
  float h[16];
  const float4* tp = (const float4*)(h1 + i * 16);
#pragma unroll
  for (int q = 0; q < 4; q++) {
    float4 v = tp[q];
    h[4 * q + 0] = v.x;
    h[4 * q + 1] = v.y;
    h[4 * q + 2] = v.z;
    h[4 * q + 3] = v.w;
  }
  float o[8];
#pragma unroll
  for (int j = 0; j < 7; j++) {
    float s = 0.f;
#pragma unroll
    for (int c = 0; c < 16; c++) s = fmaf(h[c], W2[c * 7 + j], s);
    o[j] = s * di;
  }
  o[7] = 0.f;
  float4* hp = (float4*)(hs2 + i * 8);
  hp[0] = make_float4(o[0], o[1], o[2], o[3]);
  hp[1] = make_float4(o[4], o[5], o[6], o[7]);
}

// ---- layer2 aggregation in LDS + bias + log_softmax -> out ----
__global__ __launch_bounds__(ATPB) void k_agg2(const int* __restrict__ mat,
                                               const int* __restrict__ ebuf,
                                               const float* __restrict__ hs2,
                                               const float* __restrict__ dinv,
                                               const float* __restrict__ b2,
                                               float* __restrict__ out, int n, int E, int NB) {
  __shared__ float acc[BUCKET * 8];
  int t = threadIdx.x, b = blockIdx.x;
  int base = b << 8;
  for (int i = t; i < BUCKET * 8; i += ATPB) {
    int node = base + (i >> 3);
    acc[i] = (node < n) ? hs2[node * 8 + (i & 7)] : 0.f;  // self-loop init
  }
  __syncthreads();
  int e0 = mat[b * NBLK];
  int e1 = (b + 1 < NB) ? mat[(b + 1) * NBLK] : E;
  int sub = t & 7, slot = t >> 3;  // 128 edge slots
  int e = e0 + slot;
  for (; e + 384 < e1; e += 512) {
    int p0 = ebuf[e], p1 = ebuf[e + 128], p2 = ebuf[e + 256], p3 = ebuf[e + 384];
    float v0 = hs2[(p0 & SRCMASK) * 8 + sub];
    float v1 = hs2[(p1 & SRCMASK) * 8 + sub];
    float v2 = hs2[(p2 & SRCMASK) * 8 + sub];
    float v3 = hs2[(p3 & SRCMASK) * 8 + sub];
    atomicAdd(&acc[(p0 >> 17) * 8 + sub], v0);
    atomicAdd(&acc[(p1 >> 17) * 8 + sub], v1);
    atomicAdd(&acc[(p2 >> 17) * 8 + sub], v2);
    atomicAdd(&acc[(p3 >> 17) * 8 + sub], v3);
  }
  for (; e < e1; e += 128) {
    int p = ebuf[e];
    atomicAdd(&acc[(p >> 17) * 8 + sub], hs2[(p & SRCMASK) * 8 + sub]);
  }
  __syncthreads();
  if (t < BUCKET) {
    int node = base + t;
    if (node < n) {
      float di = dinv[node];
      float v[7];
      float m = -1e30f;
#pragma unroll
      for (int j = 0; j < 7; j++) {
        v[j] = fmaf(di, acc[t * 8 + j], b2[j]);
        m = fmaxf(m, v[j]);
      }
      float s = 0.f;
#pragma unroll
      for (int j = 0; j < 7; j++) s += expf(v[j] - m);
      float lse = m + logf(s);
#pragma unroll
      for (int j = 0; j < 7; j++) out[node * 7 + j] = v[j] - lse;
    }
  }
}

}  // namespace

extern "C" void kernel_launch(void* const* d_in, const int* in_sizes, int n_in,
                              void* d_out, int out_size, void* d_ws, size_t ws_size,
                              hipStream_t stream) {
  const float* x = (const float*)d_in[0];
  const int* ei32 = (const int*)d_in[1];
  const long long* ei64 = (const long long*)d_in[1];
  const float* W1 = (const float*)d_in[2];
  const float* b1 = (const float*)d_in[3];
  const float* W2 = (const float*)d_in[4];
  const float* b2 = (const float*)d_in[5];
  float* out = (float*)d_out;

  int n = in_sizes[0] / IN_FEAT;  // 100000
  int E = in_sizes[1] / 2;        // 3200000
  int NB = (n + BUCKET - 1) / BUCKET;  // 391
  int chunk = (E + NBLK - 1) / NBLK;
  int M = NB * NBLK;

  // workspace layout (~23 MB)
  char* w = (char*)d_ws;
  int* flag = (int*)w;     w += 256;
  float* dinv = (float*)w; w += (size_t)n * 4;
  int* mat = (int*)w;      w += (size_t)M * 4 + 256;
  int* ebuf = (int*)w;     w += (size_t)E * 4;
  float* hs1 = (float*)w;  w += (size_t)n * HID * 4;
  float* h1 = (float*)w;   w += (size_t)n * HID * 4;
  float* hs2 = (float*)w;  w += (size_t)n * 8 * 4;

  int nb_n = (n + TPB - 1) / TPB;
  int nb_gemm = (n + 127) / 128;

  hipLaunchKernelGGL(k_detect, dim3(1), dim3(TPB), 0, stream, ei32, flag);
  hipLaunchKernelGGL(k_hist, dim3(NBLK), dim3(TPB), 0, stream, ei32, ei64, flag, mat, E, chunk, NB);
  hipLaunchKernelGGL(k_scan, dim3(1), dim3(ATPB), 0, stream, mat, M);
  hipLaunchKernelGGL(k_scatterE, dim3(NBLK), dim3(TPB), 0, stream, ei32, ei64, flag, mat, ebuf, E, chunk, NB);
  hipLaunchKernelGGL(k_dinv2, dim3(NB), dim3(TPB), 0, stream, mat, ebuf, dinv, n, E, NB);
  hipLaunchKernelGGL(k_gemm1, dim3(nb_gemm), dim3(GTPB), 0, stream, x, W1, dinv, hs1, n);
  hipLaunchKernelGGL(k_agg1, dim3(NB), dim3(ATPB), 0, stream, mat, ebuf, hs1, dinv, b1, h1, n, E, NB);
  hipLaunchKernelGGL(k_layer2, dim3(nb_n), dim3(TPB), 0, stream, h1, dinv, W2, hs2, n);
  hipLaunchKernelGGL(k_agg2, dim3(NB), dim3(ATPB), 0, stream, mat, ebuf, hs2, dinv, b2, out, n, E, NB);
}

// Round 4
// 859.517 us; speedup vs baseline: 1.2917x; 1.2917x over previous
//
#include <hip/hip_runtime.h>
#include <math.h>

#define TPB 256
#define GTPB 128

namespace {

constexpr int IN_FEAT = 512;
constexpr int HID = 16;

__device__ __forceinline__ void load_edge(const int* __restrict__ ei32,
                                          const long long* __restrict__ ei64,
                                          int flag, long long e, int E, int& s, int& d) {
  if (flag) {
    s = (int)ei64[e];
    d = (int)ei64[(long long)E + e];
  } else {
    s = ei32[e];
    d = ei32[(long long)E + e];
  }
}

// ---- edge dtype detect: int64 (all high words zero) vs int32 ----
__global__ void k_detect(const int* __restrict__ ei32, int* __restrict__ flag) {
  __shared__ int red[TPB];
  int t = threadIdx.x;
  int v = 0;
  for (int i = t; i < 2048; i += TPB) v |= ei32[2 * i + 1];
  red[t] = v;
  __syncthreads();
  for (int s = TPB / 2; s > 0; s >>= 1) {
    if (t < s) red[t] |= red[t + s];
    __syncthreads();
  }
  if (t == 0) *flag = (red[0] == 0) ? 1 : 0;  // 1 => int64 layout
}

__global__ void k_deg_init(float* __restrict__ deg, int n) {
  int i = blockIdx.x * TPB + threadIdx.x;
  if (i < n) deg[i] = 1.0f;  // self-loop
}

__global__ void k_deg_accum(const int* __restrict__ ei32, const long long* __restrict__ ei64,
                            const int* __restrict__ flag, float* __restrict__ deg, int E) {
  int e = blockIdx.x * TPB + threadIdx.x;
  if (e >= E) return;
  int d = (*flag) ? (int)ei64[(long long)E + e] : ei32[(long long)E + e];
  atomicAdd(&deg[d], 1.0f);
}

__global__ void k_rsqrt(float* __restrict__ deg, int n) {
  int i = blockIdx.x * TPB + threadIdx.x;
  if (i < n) deg[i] = rsqrtf(deg[i]);
}

// ---- layer1 GEMM: hs1 = (x @ W1) * dinv[row]; t1 = hs1 (self-loop init) ----
// 128-row tiles, K-chunk 64, 4x4 register block/thread, +4-float row pad.
__global__ __launch_bounds__(GTPB) void k_gemm1(const float* __restrict__ x,
                                                const float* __restrict__ W1,
                                                const float* __restrict__ dinv,
                                                float* __restrict__ hs1,
                                                float* __restrict__ t1, int n) {
  __shared__ float xs[128 * 68];
  __shared__ float wt[16 * 68];
  int t = threadIdx.x;
  int rq = t & 31, cq = t >> 5;
  float acc[4][4] = {};
  int r0 = blockIdx.x * 128;
  const float4* x4 = (const float4*)x;
  for (int ch = 0; ch < 8; ch++) {
    for (int i = t; i < 2048; i += GTPB) {
      int row = i >> 4, cc = i & 15;
      int gr = r0 + row;
      if (gr >= n) gr = n - 1;
      float4 v = x4[(long long)gr * 128 + ch * 16 + cc];
      *(float4*)&xs[row * 68 + cc * 4] = v;
    }
    for (int i = t; i < 1024; i += GTPB) {
      int kl = i >> 4, c = i & 15;
      wt[c * 68 + kl] = W1[(ch * 64 + kl) * 16 + c];
    }
    __syncthreads();
#pragma unroll 4
    for (int kk = 0; kk < 16; kk++) {
      float4 xv[4], wv[4];
#pragma unroll
      for (int ri = 0; ri < 4; ri++) xv[ri] = *(const float4*)&xs[(rq + 32 * ri) * 68 + kk * 4];
#pragma unroll
      for (int ci = 0; ci < 4; ci++) wv[ci] = *(const float4*)&wt[(4 * cq + ci) * 68 + kk * 4];
#pragma unroll
      for (int ri = 0; ri < 4; ri++)
#pragma unroll
        for (int ci = 0; ci < 4; ci++) {
          acc[ri][ci] = fmaf(xv[ri].x, wv[ci].x, acc[ri][ci]);
          acc[ri][ci] = fmaf(xv[ri].y, wv[ci].y, acc[ri][ci]);
          acc[ri][ci] = fmaf(xv[ri].z, wv[ci].z, acc[ri][ci]);
          acc[ri][ci] = fmaf(xv[ri].w, wv[ci].w, acc[ri][ci]);
        }
    }
    __syncthreads();
  }
#pragma unroll
  for (int ri = 0; ri < 4; ri++) {
    int row = r0 + rq + 32 * ri;
    if (row < n) {
      float di = dinv[row];
      float4 v = make_float4(acc[ri][0] * di, acc[ri][1] * di, acc[ri][2] * di, acc[ri][3] * di);
      *(float4*)&hs1[(long long)row * HID + 4 * cq] = v;
      *(float4*)&t1[(long long)row * HID + 4 * cq] = v;
    }
  }
}

// ---- edge scatter layer1: t1[dst][f] += hs1[src][f], 16 lanes/edge ----
__global__ void k_scatter1(const int* __restrict__ ei32, const long long* __restrict__ ei64,
                           const int* __restrict__ flag, const float* __restrict__ hs1,
                           float* __restrict__ t1, int E) {
  long long gid = (long long)blockIdx.x * TPB + threadIdx.x;
  long long e = gid >> 4;
  if (e >= E) return;
  int f = (int)(gid & 15);
  int s, d;
  load_edge(ei32, ei64, *flag, e, E, s, d);
  atomicAdd(&t1[(long long)d * HID + f], hs1[(long long)s * HID + f]);
}

// ---- layer1 epilogue + layer2 GEMM: h1 = relu(dinv*t1 + b1); hs2 = (h1@W2)*dinv; t2 = hs2 ----
__global__ void k_layer2(const float* __restrict__ t1, const float* __restrict__ dinv,
                         const float* __restrict__ b1, const float* __restrict__ W2,
                         float* __restrict__ hs2, float* __restrict__ t2, int n) {
  int i = blockIdx.x * TPB + threadIdx.x;
  if (i >= n) return;
  float di = dinv[i];
  float h[16];
  const float4* tp = (const float4*)(t1 + (long long)i * HID);
#pragma unroll
  for (int q = 0; q < 4; q++) {
    float4 v = tp[q];
    float4 b = ((const float4*)b1)[q];
    h[4 * q + 0] = fmaxf(fmaf(di, v.x, b.x), 0.f);
    h[4 * q + 1] = fmaxf(fmaf(di, v.y, b.y), 0.f);
    h[4 * q + 2] = fmaxf(fmaf(di, v.z, b.z), 0.f);
    h[4 * q + 3] = fmaxf(fmaf(di, v.w, b.w), 0.f);
  }
  float o[8];
#pragma unroll
  for (int j = 0; j < 7; j++) {
    float s = 0.f;
#pragma unroll
    for (int c = 0; c < 16; c++) s = fmaf(h[c], W2[c * 7 + j], s);
    o[j] = s * di;
  }
  o[7] = 0.f;
  float4 lo = make_float4(o[0], o[1], o[2], o[3]);
  float4 hi = make_float4(o[4], o[5], o[6], o[7]);
  float4* hp = (float4*)(hs2 + (long long)i * 8);
  float4* qp = (float4*)(t2 + (long long)i * 8);
  hp[0] = lo; hp[1] = hi;
  qp[0] = lo; qp[1] = hi;
}

// ---- edge scatter layer2: t2[dst][f] += hs2[src][f], 8 lanes/edge (f<7 active) ----
__global__ void k_scatter2(const int* __restrict__ ei32, const long long* __restrict__ ei64,
                           const int* __restrict__ flag, const float* __restrict__ hs2,
                           float* __restrict__ t2, int E) {
  long long gid = (long long)blockIdx.x * TPB + threadIdx.x;
  long long e = gid >> 3;
  if (e >= E) return;
  int f = (int)(gid & 7);
  if (f == 7) return;
  int s, d;
  load_edge(ei32, ei64, *flag, e, E, s, d);
  atomicAdd(&t2[(long long)d * 8 + f], hs2[(long long)s * 8 + f]);
}

// ---- finalize: logits = dinv*t2 + b2; log_softmax ----
__global__ void k_final(const float* __restrict__ t2, const float* __restrict__ dinv,
                        const float* __restrict__ b2, float* __restrict__ out, int n) {
  int i = blockIdx.x * TPB + threadIdx.x;
  if (i >= n) return;
  float di = dinv[i];
  float v[7];
  float m = -1e30f;
#pragma unroll
  for (int j = 0; j < 7; j++) {
    v[j] = fmaf(di, t2[(long long)i * 8 + j], b2[j]);
    m = fmaxf(m, v[j]);
  }
  float s = 0.f;
#pragma unroll
  for (int j = 0; j < 7; j++) s += expf(v[j] - m);
  float lse = m + logf(s);
#pragma unroll
  for (int j = 0; j < 7; j++) out[(long long)i * 7 + j] = v[j] - lse;
}

}  // namespace

extern "C" void kernel_launch(void* const* d_in, const int* in_sizes, int n_in,
                              void* d_out, int out_size, void* d_ws, size_t ws_size,
                              hipStream_t stream) {
  const float* x = (const float*)d_in[0];
  const int* ei32 = (const int*)d_in[1];
  const long long* ei64 = (const long long*)d_in[1];
  const float* W1 = (const float*)d_in[2];
  const float* b1 = (const float*)d_in[3];
  const float* W2 = (const float*)d_in[4];
  const float* b2 = (const float*)d_in[5];
  float* out = (float*)d_out;

  int n = in_sizes[0] / IN_FEAT;  // 100000
  int E = in_sizes[1] / 2;        // 3200000

  // workspace layout (~20 MB)
  char* w = (char*)d_ws;
  int* flag = (int*)w;     w += 256;
  float* dinv = (float*)w; w += (size_t)n * 4;
  float* hs1 = (float*)w;  w += (size_t)n * HID * 4;
  float* t1 = (float*)w;   w += (size_t)n * HID * 4;
  float* hs2 = (float*)w;  w += (size_t)n * 8 * 4;
  float* t2 = (float*)w;   w += (size_t)n * 8 * 4;

  int nb_n = (n + TPB - 1) / TPB;
  int nb_e = (E + TPB - 1) / TPB;
  int nb_gemm = (n + 127) / 128;
  long long w1 = (long long)E * 16, w2 = (long long)E * 8;
  int nb_s1 = (int)((w1 + TPB - 1) / TPB);
  int nb_s2 = (int)((w2 + TPB - 1) / TPB);

  hipLaunchKernelGGL(k_detect, dim3(1), dim3(TPB), 0, stream, ei32, flag);
  hipLaunchKernelGGL(k_deg_init, dim3(nb_n), dim3(TPB), 0, stream, dinv, n);
  hipLaunchKernelGGL(k_deg_accum, dim3(nb_e), dim3(TPB), 0, stream, ei32, ei64, flag, dinv, E);
  hipLaunchKernelGGL(k_rsqrt, dim3(nb_n), dim3(TPB), 0, stream, dinv, n);
  hipLaunchKernelGGL(k_gemm1, dim3(nb_gemm), dim3(GTPB), 0, stream, x, W1, dinv, hs1, t1, n);
  hipLaunchKernelGGL(k_scatter1, dim3(nb_s1), dim3(TPB), 0, stream, ei32, ei64, flag, hs1, t1, E);
  hipLaunchKernelGGL(k_layer2, dim3(nb_n), dim3(TPB), 0, stream, t1, dinv, b1, W2, hs2, t2, n);
  hipLaunchKernelGGL(k_scatter2, dim3(nb_s2), dim3(TPB), 0, stream, ei32, ei64, flag, hs2, t2, E);
  hipLaunchKernelGGL(k_final, dim3(nb_n), dim3(TPB), 0, stream, t2, dinv, b2, out, n);
}

// Round 5
// 844.654 us; speedup vs baseline: 1.3144x; 1.0176x over previous
//
#include <hip/hip_runtime.h>
#include <hip/hip_fp16.h>
#include <math.h>

#define TPB 256
#define GTPB 128

namespace {

constexpr int IN_FEAT = 512;
constexpr int HID = 16;

__device__ __forceinline__ void load_edge(const int* __restrict__ ei32,
                                          const long long* __restrict__ ei64,
                                          int flag, long long e, int E, int& s, int& d) {
  if (flag) {
    s = (int)ei64[e];
    d = (int)ei64[(long long)E + e];
  } else {
    s = ei32[e];
    d = ei32[(long long)E + e];
  }
}

// ---- edge dtype detect: int64 (all high words zero) vs int32 ----
__global__ void k_detect(const int* __restrict__ ei32, int* __restrict__ flag) {
  __shared__ int red[TPB];
  int t = threadIdx.x;
  int v = 0;
  for (int i = t; i < 2048; i += TPB) v |= ei32[2 * i + 1];
  red[t] = v;
  __syncthreads();
  for (int s = TPB / 2; s > 0; s >>= 1) {
    if (t < s) red[t] |= red[t + s];
    __syncthreads();
  }
  if (t == 0) *flag = (red[0] == 0) ? 1 : 0;  // 1 => int64 layout
}

__global__ void k_deg_init(float* __restrict__ deg, int n) {
  int i = blockIdx.x * TPB + threadIdx.x;
  if (i < n) deg[i] = 1.0f;  // self-loop
}

// ---- fused: pack edges to int2 + degree count ----
__global__ void k_prep(const int* __restrict__ ei32, const long long* __restrict__ ei64,
                       const int* __restrict__ flag, int2* __restrict__ epk,
                       float* __restrict__ deg, int E) {
  int e = blockIdx.x * TPB + threadIdx.x;
  if (e >= E) return;
  int s, d;
  load_edge(ei32, ei64, *flag, e, E, s, d);
  epk[e] = make_int2(s, d);
  atomicAdd(&deg[d], 1.0f);
}

__global__ void k_rsqrt(float* __restrict__ deg, int n) {
  int i = blockIdx.x * TPB + threadIdx.x;
  if (i < n) deg[i] = rsqrtf(deg[i]);
}

// ---- layer1 GEMM: hs1 = fp16((x @ W1) * dinv[row]); t1 = hs1 (self-loop init) ----
__global__ __launch_bounds__(GTPB) void k_gemm1(const float* __restrict__ x,
                                                const float* __restrict__ W1,
                                                const float* __restrict__ dinv,
                                                __half2* __restrict__ hs1h,
                                                __half2* __restrict__ t1h, int n) {
  __shared__ float xs[128 * 68];
  __shared__ float wt[16 * 68];
  int t = threadIdx.x;
  int rq = t & 31, cq = t >> 5;
  float acc[4][4] = {};
  int r0 = blockIdx.x * 128;
  const float4* x4 = (const float4*)x;
  for (int ch = 0; ch < 8; ch++) {
    for (int i = t; i < 2048; i += GTPB) {
      int row = i >> 4, cc = i & 15;
      int gr = r0 + row;
      if (gr >= n) gr = n - 1;
      float4 v = x4[(long long)gr * 128 + ch * 16 + cc];
      *(float4*)&xs[row * 68 + cc * 4] = v;
    }
    for (int i = t; i < 1024; i += GTPB) {
      int kl = i >> 4, c = i & 15;
      wt[c * 68 + kl] = W1[(ch * 64 + kl) * 16 + c];
    }
    __syncthreads();
#pragma unroll 4
    for (int kk = 0; kk < 16; kk++) {
      float4 xv[4], wv[4];
#pragma unroll
      for (int ri = 0; ri < 4; ri++) xv[ri] = *(const float4*)&xs[(rq + 32 * ri) * 68 + kk * 4];
#pragma unroll
      for (int ci = 0; ci < 4; ci++) wv[ci] = *(const float4*)&wt[(4 * cq + ci) * 68 + kk * 4];
#pragma unroll
      for (int ri = 0; ri < 4; ri++)
#pragma unroll
        for (int ci = 0; ci < 4; ci++) {
          acc[ri][ci] = fmaf(xv[ri].x, wv[ci].x, acc[ri][ci]);
          acc[ri][ci] = fmaf(xv[ri].y, wv[ci].y, acc[ri][ci]);
          acc[ri][ci] = fmaf(xv[ri].z, wv[ci].z, acc[ri][ci]);
          acc[ri][ci] = fmaf(xv[ri].w, wv[ci].w, acc[ri][ci]);
        }
    }
    __syncthreads();
  }
#pragma unroll
  for (int ri = 0; ri < 4; ri++) {
    int row = r0 + rq + 32 * ri;
    if (row < n) {
      float di = dinv[row];
      __half2 a = __floats2half2_rn(acc[ri][0] * di, acc[ri][1] * di);
      __half2 b = __floats2half2_rn(acc[ri][2] * di, acc[ri][3] * di);
      long long base = (long long)row * 8 + cq * 2;
      hs1h[base] = a;
      hs1h[base + 1] = b;
      t1h[base] = a;
      t1h[base + 1] = b;
    }
  }
}

// ---- edge scatter layer1: t1[dst] += hs1[src], 8 half2 lanes/edge ----
__global__ void k_scatter1(const int2* __restrict__ epk, const __half2* __restrict__ hs1h,
                           __half2* __restrict__ t1h, int E) {
  long long gid = (long long)blockIdx.x * TPB + threadIdx.x;
  long long e = gid >> 3;
  if (e >= E) return;
  int f = (int)(gid & 7);
  int2 ed = epk[e];
  __half2 v = hs1h[(long long)ed.x * 8 + f];
  unsafeAtomicAdd(&t1h[(long long)ed.y * 8 + f], v);
}

// ---- layer1 epilogue + layer2 transform ----
__global__ void k_layer2(const __half2* __restrict__ t1h, const float* __restrict__ dinv,
                         const float* __restrict__ b1, const float* __restrict__ W2,
                         __half2* __restrict__ hs2h, __half2* __restrict__ t2h, int n) {
  int i = blockIdx.x * TPB + threadIdx.x;
  if (i >= n) return;
  float di = dinv[i];
  float h[16];
  const __half2* tp = t1h + (long long)i * 8;
#pragma unroll
  for (int q = 0; q < 8; q++) {
    float2 v = __half22float2(tp[q]);
    h[2 * q + 0] = fmaxf(fmaf(di, v.x, b1[2 * q + 0]), 0.f);
    h[2 * q + 1] = fmaxf(fmaf(di, v.y, b1[2 * q + 1]), 0.f);
  }
  float o[8];
#pragma unroll
  for (int j = 0; j < 7; j++) {
    float s = 0.f;
#pragma unroll
    for (int c = 0; c < 16; c++) s = fmaf(h[c], W2[c * 7 + j], s);
    o[j] = s * di;
  }
  o[7] = 0.f;
  __half2* hp = hs2h + (long long)i * 4;
  __half2* qp = t2h + (long long)i * 4;
#pragma unroll
  for (int q = 0; q < 4; q++) {
    __half2 v = __floats2half2_rn(o[2 * q], o[2 * q + 1]);
    hp[q] = v;
    qp[q] = v;
  }
}

// ---- edge scatter layer2: t2[dst] += hs2[src], 4 half2 lanes/edge ----
__global__ void k_scatter2(const int2* __restrict__ epk, const __half2* __restrict__ hs2h,
                           __half2* __restrict__ t2h, int E) {
  long long gid = (long long)blockIdx.x * TPB + threadIdx.x;
  long long e = gid >> 2;
  if (e >= E) return;
  int f = (int)(gid & 3);
  int2 ed = epk[e];
  __half2 v = hs2h[(long long)ed.x * 4 + f];
  unsafeAtomicAdd(&t2h[(long long)ed.y * 4 + f], v);
}

// ---- finalize: logits = dinv*t2 + b2; log_softmax ----
__global__ void k_final(const __half2* __restrict__ t2h, const float* __restrict__ dinv,
                        const float* __restrict__ b2, float* __restrict__ out, int n) {
  int i = blockIdx.x * TPB + threadIdx.x;
  if (i >= n) return;
  float di = dinv[i];
  const __half2* tp = t2h + (long long)i * 4;
  float a[8];
#pragma unroll
  for (int q = 0; q < 4; q++) {
    float2 v = __half22float2(tp[q]);
    a[2 * q] = v.x;
    a[2 * q + 1] = v.y;
  }
  float v[7];
  float m = -1e30f;
#pragma unroll
  for (int j = 0; j < 7; j++) {
    v[j] = fmaf(di, a[j], b2[j]);
    m = fmaxf(m, v[j]);
  }
  float s = 0.f;
#pragma unroll
  for (int j = 0; j < 7; j++) s += expf(v[j] - m);
  float lse = m + logf(s);
#pragma unroll
  for (int j = 0; j < 7; j++) out[(long long)i * 7 + j] = v[j] - lse;
}

}  // namespace

extern "C" void kernel_launch(void* const* d_in, const int* in_sizes, int n_in,
                              void* d_out, int out_size, void* d_ws, size_t ws_size,
                              hipStream_t stream) {
  const float* x = (const float*)d_in[0];
  const int* ei32 = (const int*)d_in[1];
  const long long* ei64 = (const long long*)d_in[1];
  const float* W1 = (const float*)d_in[2];
  const float* b1 = (const float*)d_in[3];
  const float* W2 = (const float*)d_in[4];
  const float* b2 = (const float*)d_in[5];
  float* out = (float*)d_out;

  int n = in_sizes[0] / IN_FEAT;  // 100000
  int E = in_sizes[1] / 2;        // 3200000

  // workspace layout (~36 MB)
  char* w = (char*)d_ws;
  int* flag = (int*)w;       w += 256;
  float* dinv = (float*)w;   w += (size_t)n * 4;  // 400000 (8B-aligned)
  int2* epk = (int2*)w;      w += (size_t)E * 8;
  __half2* hs1h = (__half2*)w; w += (size_t)n * 32;
  __half2* t1h = (__half2*)w;  w += (size_t)n * 32;
  __half2* hs2h = (__half2*)w; w += (size_t)n * 16;
  __half2* t2h = (__half2*)w;  w += (size_t)n * 16;

  int nb_n = (n + TPB - 1) / TPB;
  int nb_e = (E + TPB - 1) / TPB;
  int nb_gemm = (n + 127) / 128;
  long long l1 = (long long)E * 8, l2 = (long long)E * 4;
  int nb_s1 = (int)((l1 + TPB - 1) / TPB);
  int nb_s2 = (int)((l2 + TPB - 1) / TPB);

  hipLaunchKernelGGL(k_detect, dim3(1), dim3(TPB), 0, stream, ei32, flag);
  hipLaunchKernelGGL(k_deg_init, dim3(nb_n), dim3(TPB), 0, stream, dinv, n);
  hipLaunchKernelGGL(k_prep, dim3(nb_e), dim3(TPB), 0, stream, ei32, ei64, flag, epk, dinv, E);
  hipLaunchKernelGGL(k_rsqrt, dim3(nb_n), dim3(TPB), 0, stream, dinv, n);
  hipLaunchKernelGGL(k_gemm1, dim3(nb_gemm), dim3(GTPB), 0, stream, x, W1, dinv, hs1h, t1h, n);
  hipLaunchKernelGGL(k_scatter1, dim3(nb_s1), dim3(TPB), 0, stream, epk, hs1h, t1h, E);
  hipLaunchKernelGGL(k_layer2, dim3(nb_n), dim3(TPB), 0, stream, t1h, dinv, b1, W2, hs2h, t2h, n);
  hipLaunchKernelGGL(k_scatter2, dim3(nb_s2), dim3(TPB), 0, stream, epk, hs2h, t2h, E);
  hipLaunchKernelGGL(k_final, dim3(nb_n), dim3(TPB), 0, stream, t2h, dinv, b2, out, n);
}